// Round 1
// baseline (3748.502 us; speedup 1.0000x reference)
//
#include <hip/hip_runtime.h>
#include <hip/hip_bf16.h>

#define N_NODES 10000
#define N_EDGES 320000
#define EPB 8          // edges per block in edge kernel
#define KV_PAD 328     // 324 padded to /4

// ---------------- helpers ----------------
__device__ inline float wave_reduce_sum64(float v) {
    #pragma unroll
    for (int o = 32; o > 0; o >>= 1) v += __shfl_down(v, o, 64);
    return v;
}

// block of 128 threads (2 waves): sum-reduce a float4 across the block
__device__ inline void block_reduce4(float4& v, float4* red) {
    #pragma unroll
    for (int o = 32; o > 0; o >>= 1) {
        v.x += __shfl_down(v.x, o, 64);
        v.y += __shfl_down(v.y, o, 64);
        v.z += __shfl_down(v.z, o, 64);
        v.w += __shfl_down(v.w, o, 64);
    }
    __syncthreads();
    if ((threadIdx.x & 63) == 0) red[threadIdx.x >> 6] = v;
    __syncthreads();
    float4 a = red[0], b = red[1];
    v.x = a.x + b.x; v.y = a.y + b.y; v.z = a.z + b.z; v.w = a.w + b.w;
}

// ---------------- q = MLP_hq(h) ----------------
__global__ __launch_bounds__(128) void q_kernel(
    const float* __restrict__ h,
    const float* __restrict__ W1, const float* __restrict__ b1,
    const float* __restrict__ g1, const float* __restrict__ be1,
    const float* __restrict__ W2, const float* __restrict__ b2,
    float* __restrict__ qout)
{
    __shared__ __align__(16) float x[128];
    __shared__ __align__(16) float r[128];
    __shared__ float4 red4[2];
    int n = blockIdx.x, tid = threadIdx.x;
    x[tid] = h[(long)n * 128 + tid];
    __syncthreads();
    float y = b1[tid];
    #pragma unroll 4
    for (int i4 = 0; i4 < 128; i4 += 4) {
        float4 c = *(const float4*)&x[i4];
        y = fmaf(c.x, W1[(i4 + 0) * 128 + tid], y);
        y = fmaf(c.y, W1[(i4 + 1) * 128 + tid], y);
        y = fmaf(c.z, W1[(i4 + 2) * 128 + tid], y);
        y = fmaf(c.w, W1[(i4 + 3) * 128 + tid], y);
    }
    float4 s = make_float4(y, y * y, 0.f, 0.f);
    block_reduce4(s, red4);
    float mu  = s.x * 0.0078125f;
    float var = s.y * 0.0078125f - mu * mu;
    float ny = (y - mu) * rsqrtf(var + 1e-5f) * g1[tid] + be1[tid];
    r[tid] = fmaxf(ny, 0.f);
    __syncthreads();
    float y2 = b2[tid];
    #pragma unroll 4
    for (int i4 = 0; i4 < 128; i4 += 4) {
        float4 c = *(const float4*)&r[i4];
        y2 = fmaf(c.x, W2[(i4 + 0) * 128 + tid], y2);
        y2 = fmaf(c.y, W2[(i4 + 1) * 128 + tid], y2);
        y2 = fmaf(c.z, W2[(i4 + 2) * 128 + tid], y2);
        y2 = fmaf(c.w, W2[(i4 + 3) * 128 + tid], y2);
    }
    qout[(long)n * 128 + tid] = y2;
}

// ---------------- edge kernel: kv gather, hk/hv MLPs, e_w, logits ----------------
__global__ __launch_bounds__(128) void edge_kernel(
    const float* __restrict__ h, const float* __restrict__ r_feat,
    const float* __restrict__ edge_feat, const int* __restrict__ edge_index,
    const float* __restrict__ kW1, const float* __restrict__ kb1,
    const float* __restrict__ kg1, const float* __restrict__ kbe1,
    const float* __restrict__ kW2, const float* __restrict__ kb2,
    const float* __restrict__ vW1, const float* __restrict__ vb1,
    const float* __restrict__ vg1, const float* __restrict__ vbe1,
    const float* __restrict__ vW2, const float* __restrict__ vb2,
    const float* __restrict__ ewW, const float* __restrict__ ewb,
    const float* __restrict__ q,
    float* __restrict__ logits, __hip_bfloat16* __restrict__ vout,
    unsigned int* __restrict__ segmax_u)
{
    __shared__ __align__(16) float kv[EPB][KV_PAD];
    __shared__ __align__(16) float rk[EPB][128];
    __shared__ __align__(16) float rv[EPB][128];
    __shared__ float4 red4[2];
    __shared__ float ew_s[EPB];
    __shared__ int dst_s[EPB];

    int tid = threadIdx.x;
    long eg0 = (long)blockIdx.x * EPB;

    // gather kv = [edge_feat(4) | r_feat(64) | h[dst](128) | h[src](128)]
    #pragma unroll
    for (int e = 0; e < EPB; ++e) {
        long eg = eg0 + e;
        int srcn = edge_index[eg];
        int dstn = edge_index[N_EDGES + eg];
        if (tid == 0) dst_s[e] = dstn;
        if (tid < 4)  kv[e][tid] = edge_feat[eg * 4 + tid];
        if (tid < 64) kv[e][4 + tid] = r_feat[eg * 64 + tid];
        kv[e][68 + tid]  = h[(long)dstn * 128 + tid];
        kv[e][196 + tid] = h[(long)srcn * 128 + tid];
    }
    __syncthreads();

    // e_w = sigmoid(r_feat @ ew_W + ew_b), wave 0 only
    if (tid < 64) {
        float w = ewW[tid];
        float bb = ewb[0];
        #pragma unroll
        for (int e = 0; e < EPB; ++e) {
            float p = kv[e][4 + tid] * w;
            p = wave_reduce_sum64(p);
            if (tid == 0) ew_s[e] = 1.f / (1.f + expf(-(p + bb)));
        }
    }
    __syncthreads();

    // first GEMV: hidden = kv @ W1 + b1  (both k and v nets)
    float hk[EPB], hv[EPB];
    {
        float bk = kb1[tid], bv = vb1[tid];
        #pragma unroll
        for (int e = 0; e < EPB; ++e) { hk[e] = bk; hv[e] = bv; }
    }
    for (int i4 = 0; i4 < 324; i4 += 4) {   // 81 iterations
        float4 c[EPB];
        #pragma unroll
        for (int e = 0; e < EPB; ++e) c[e] = *(const float4*)&kv[e][i4];
        #pragma unroll
        for (int ii = 0; ii < 4; ++ii) {
            float wk = kW1[(i4 + ii) * 128 + tid];
            float wv = vW1[(i4 + ii) * 128 + tid];
            #pragma unroll
            for (int e = 0; e < EPB; ++e) {
                float x = (ii == 0) ? c[e].x : (ii == 1) ? c[e].y : (ii == 2) ? c[e].z : c[e].w;
                hk[e] = fmaf(x, wk, hk[e]);
                hv[e] = fmaf(x, wv, hv[e]);
            }
        }
    }

    // LayerNorm + ReLU for both nets, write to LDS for second GEMV
    {
        float kg = kg1[tid], kbe = kbe1[tid], vg = vg1[tid], vbe = vbe1[tid];
        #pragma unroll 1
        for (int e = 0; e < EPB; ++e) {
            float4 s = make_float4(hk[e], hk[e] * hk[e], hv[e], hv[e] * hv[e]);
            block_reduce4(s, red4);
            float muk = s.x * 0.0078125f;
            float vark = s.y * 0.0078125f - muk * muk;
            float muv = s.z * 0.0078125f;
            float varv = s.w * 0.0078125f - muv * muv;
            float nk = (hk[e] - muk) * rsqrtf(vark + 1e-5f) * kg + kbe;
            float nv = (hv[e] - muv) * rsqrtf(varv + 1e-5f) * vg + vbe;
            rk[e][tid] = fmaxf(nk, 0.f);
            rv[e][tid] = fmaxf(nv, 0.f);
        }
    }
    __syncthreads();

    // second GEMV: out = relu @ W2 + b2
    float k2[EPB], v2[EPB];
    {
        float bk = kb2[tid], bv = vb2[tid];
        #pragma unroll
        for (int e = 0; e < EPB; ++e) { k2[e] = bk; v2[e] = bv; }
    }
    for (int i4 = 0; i4 < 128; i4 += 4) {   // 32 iterations
        float4 ck[EPB], cv[EPB];
        #pragma unroll
        for (int e = 0; e < EPB; ++e) {
            ck[e] = *(const float4*)&rk[e][i4];
            cv[e] = *(const float4*)&rv[e][i4];
        }
        #pragma unroll
        for (int ii = 0; ii < 4; ++ii) {
            float wk = kW2[(i4 + ii) * 128 + tid];
            float wv = vW2[(i4 + ii) * 128 + tid];
            #pragma unroll
            for (int e = 0; e < EPB; ++e) {
                float xk = (ii == 0) ? ck[e].x : (ii == 1) ? ck[e].y : (ii == 2) ? ck[e].z : ck[e].w;
                float xv = (ii == 0) ? cv[e].x : (ii == 1) ? cv[e].y : (ii == 2) ? cv[e].z : cv[e].w;
                k2[e] = fmaf(xk, wk, k2[e]);
                v2[e] = fmaf(xv, wv, v2[e]);
            }
        }
    }

    // logits per (edge, head) + segmax atomicMax; store v (scaled) as bf16
    #pragma unroll 1
    for (int e = 0; e < EPB; ++e) {
        int dstn = dst_s[e];
        long eg = eg0 + e;
        float p = q[(long)dstn * 128 + tid] * k2[e];
        p += __shfl_down(p, 4, 8);
        p += __shfl_down(p, 2, 8);
        p += __shfl_down(p, 1, 8);
        if ((tid & 7) == 0) {
            float lg = p * 0.35355339059327373f;   // 1/sqrt(8)
            int hd = tid >> 3;
            logits[eg * 16 + hd] = lg;
            unsigned int u = __float_as_uint(lg);
            unsigned int key = (u & 0x80000000u) ? ~u : (u | 0x80000000u);
            atomicMax(&segmax_u[(long)dstn * 16 + hd], key);
        }
        vout[eg * 128 + tid] = __float2bfloat16(v2[e] * ew_s[e]);
    }
}

// ---------------- scatter: exp, den, weighted v accumulation ----------------
__global__ __launch_bounds__(256) void scatter_kernel(
    const int* __restrict__ edge_index,
    const float* __restrict__ logits,
    const __hip_bfloat16* __restrict__ vout,
    const unsigned int* __restrict__ segmax_u,
    float* __restrict__ den, float* __restrict__ accum)
{
    long total = (long)N_EDGES * 16;
    long stride = (long)gridDim.x * blockDim.x;
    for (long idx = (long)blockIdx.x * blockDim.x + threadIdx.x; idx < total; idx += stride) {
        int e = (int)(idx >> 4);
        int hd = (int)(idx & 15);
        int dstn = edge_index[N_EDGES + e];
        unsigned int key = segmax_u[(long)dstn * 16 + hd];
        unsigned int u = (key & 0x80000000u) ? (key & 0x7FFFFFFFu) : ~key;
        float m = __uint_as_float(u);
        float ex = expf(logits[idx] - m);
        atomicAdd(&den[(long)dstn * 16 + hd], ex);
        const __hip_bfloat16* vp = vout + (long)e * 128 + hd * 8;
        float* ap = accum + (long)dstn * 128 + hd * 8;
        #pragma unroll
        for (int d = 0; d < 8; ++d) {
            float vv = __bfloat162float(vp[d]);
            atomicAdd(&ap[d], ex * vv);
        }
    }
}

// ---------------- output MLP + residual ----------------
__global__ __launch_bounds__(128) void out_kernel(
    const float* __restrict__ h,
    const float* __restrict__ accum, const float* __restrict__ den,
    const float* __restrict__ W1, const float* __restrict__ b1,
    const float* __restrict__ g1, const float* __restrict__ be1,
    const float* __restrict__ W2, const float* __restrict__ b2,
    float* __restrict__ out)
{
    __shared__ __align__(16) float xin[256];
    __shared__ __align__(16) float r[128];
    __shared__ float4 red4[2];
    int n = blockIdx.x, tid = threadIdx.x;
    float d = den[(long)n * 16 + (tid >> 3)];
    float hval = h[(long)n * 128 + tid];
    xin[tid] = accum[(long)n * 128 + tid] / (d + 1e-16f);
    xin[128 + tid] = hval;
    __syncthreads();
    float y = b1[tid];
    #pragma unroll 4
    for (int i4 = 0; i4 < 256; i4 += 4) {
        float4 c = *(const float4*)&xin[i4];
        y = fmaf(c.x, W1[(i4 + 0) * 128 + tid], y);
        y = fmaf(c.y, W1[(i4 + 1) * 128 + tid], y);
        y = fmaf(c.z, W1[(i4 + 2) * 128 + tid], y);
        y = fmaf(c.w, W1[(i4 + 3) * 128 + tid], y);
    }
    float4 s = make_float4(y, y * y, 0.f, 0.f);
    block_reduce4(s, red4);
    float mu  = s.x * 0.0078125f;
    float var = s.y * 0.0078125f - mu * mu;
    float ny = (y - mu) * rsqrtf(var + 1e-5f) * g1[tid] + be1[tid];
    r[tid] = fmaxf(ny, 0.f);
    __syncthreads();
    float y2 = b2[tid];
    #pragma unroll 4
    for (int i4 = 0; i4 < 128; i4 += 4) {
        float4 c = *(const float4*)&r[i4];
        y2 = fmaf(c.x, W2[(i4 + 0) * 128 + tid], y2);
        y2 = fmaf(c.y, W2[(i4 + 1) * 128 + tid], y2);
        y2 = fmaf(c.z, W2[(i4 + 2) * 128 + tid], y2);
        y2 = fmaf(c.w, W2[(i4 + 3) * 128 + tid], y2);
    }
    out[(long)n * 128 + tid] = y2 + hval;
}

// ---------------- host ----------------
extern "C" void kernel_launch(void* const* d_in, const int* in_sizes, int n_in,
                              void* d_out, int out_size, void* d_ws, size_t ws_size,
                              hipStream_t stream) {
    (void)in_sizes; (void)n_in; (void)out_size; (void)ws_size;
    const float* h         = (const float*)d_in[0];
    const float* r_feat    = (const float*)d_in[1];
    const float* edge_feat = (const float*)d_in[2];
    const int*   edge_index= (const int*)d_in[3];
    const float* kW1 = (const float*)d_in[4],  *kb1 = (const float*)d_in[5];
    const float* kg1 = (const float*)d_in[6],  *kbe1= (const float*)d_in[7];
    const float* kW2 = (const float*)d_in[8],  *kb2 = (const float*)d_in[9];
    const float* vW1 = (const float*)d_in[10], *vb1 = (const float*)d_in[11];
    const float* vg1 = (const float*)d_in[12], *vbe1= (const float*)d_in[13];
    const float* vW2 = (const float*)d_in[14], *vb2 = (const float*)d_in[15];
    const float* qW1 = (const float*)d_in[16], *qb1 = (const float*)d_in[17];
    const float* qg1 = (const float*)d_in[18], *qbe1= (const float*)d_in[19];
    const float* qW2 = (const float*)d_in[20], *qb2 = (const float*)d_in[21];
    const float* oW1 = (const float*)d_in[22], *ob1 = (const float*)d_in[23];
    const float* og1 = (const float*)d_in[24], *obe1= (const float*)d_in[25];
    const float* oW2 = (const float*)d_in[26], *ob2 = (const float*)d_in[27];
    const float* ewW = (const float*)d_in[28], *ewb = (const float*)d_in[29];
    float* out = (float*)d_out;

    char* ws = (char*)d_ws;
    size_t off = 0;
    float* q = (float*)(ws + off);            off += (size_t)N_NODES * 128 * 4;   // 5.12 MB
    float* logits = (float*)(ws + off);       off += (size_t)N_EDGES * 16 * 4;    // 20.48 MB
    __hip_bfloat16* vout = (__hip_bfloat16*)(ws + off); off += (size_t)N_EDGES * 128 * 2; // 81.92 MB
    unsigned int* segmax_u = (unsigned int*)(ws + off); size_t zbase = off;
    off += (size_t)N_NODES * 16 * 4;
    float* den = (float*)(ws + off);          off += (size_t)N_NODES * 16 * 4;
    float* accum = (float*)(ws + off);        off += (size_t)N_NODES * 128 * 4;
    size_t zbytes = off - zbase;  // segmax + den + accum contiguous

    hipMemsetAsync(ws + zbase, 0, zbytes, stream);

    q_kernel<<<N_NODES, 128, 0, stream>>>(h, qW1, qb1, qg1, qbe1, qW2, qb2, q);

    edge_kernel<<<N_EDGES / EPB, 128, 0, stream>>>(
        h, r_feat, edge_feat, edge_index,
        kW1, kb1, kg1, kbe1, kW2, kb2,
        vW1, vb1, vg1, vbe1, vW2, vb2,
        ewW, ewb, q, logits, vout, segmax_u);

    scatter_kernel<<<2048, 256, 0, stream>>>(edge_index, logits, vout, segmax_u, den, accum);

    out_kernel<<<N_NODES, 128, 0, stream>>>(h, accum, den, oW1, ob1, og1, obe1, oW2, ob2, out);
}

// Round 6
// 742.966 us; speedup vs baseline: 5.0453x; 5.0453x over previous
//
#include <hip/hip_runtime.h>
#include <hip/hip_bf16.h>

#define N_NODES 10000
#define N_EDGES 320000

typedef __attribute__((ext_vector_type(8))) short bf16x8;
typedef __attribute__((ext_vector_type(4))) float f32x4;

__device__ inline short f2bf(float x) {
    __hip_bfloat16 h = __float2bfloat16(x);
    union { __hip_bfloat16 h; short s; } u; u.h = h; return u.s;
}

__device__ inline void st_bf4(short* p, float4 v) {
    union { short s[4]; int2 i; } u;
    u.s[0] = f2bf(v.x); u.s[1] = f2bf(v.y); u.s[2] = f2bf(v.z); u.s[3] = f2bf(v.w);
    *(int2*)p = u.i;
}

__device__ inline void block_reduce4(float4& v, float4* red) {
    #pragma unroll
    for (int o = 32; o > 0; o >>= 1) {
        v.x += __shfl_down(v.x, o, 64);
        v.y += __shfl_down(v.y, o, 64);
        v.z += __shfl_down(v.z, o, 64);
        v.w += __shfl_down(v.w, o, 64);
    }
    __syncthreads();
    if ((threadIdx.x & 63) == 0) red[threadIdx.x >> 6] = v;
    __syncthreads();
    float4 a = red[0], b = red[1];
    v.x = a.x + b.x; v.y = a.y + b.y; v.z = a.z + b.z; v.w = a.w + b.w;
}

// ---------------- weight prep: [nch][256 cols][40 k] bf16, zero-padded ----------------
__global__ __launch_bounds__(256) void prep_wt_kernel(
    const float* __restrict__ Wk, const float* __restrict__ Wv,
    short* __restrict__ Wt, int K)
{
    int col = threadIdx.x, ch = blockIdx.x;
    const float* W = (col < 128) ? Wk : Wv;
    int c = col & 127;
    short tmp[40];
    #pragma unroll
    for (int kk = 0; kk < 40; ++kk) {
        int k = ch * 32 + kk;
        float w = (kk < 32 && k < K) ? W[k * 128 + c] : 0.f;
        tmp[kk] = f2bf(w);
    }
    short* outp = Wt + ((size_t)ch * 256 + col) * 40;
    #pragma unroll
    for (int i = 0; i < 5; ++i) {
        union { short s[8]; int4 v; } u;
        #pragma unroll
        for (int j = 0; j < 8; ++j) u.s[j] = tmp[i * 8 + j];
        *(int4*)(outp + i * 8) = u.v;
    }
}

// ---------------- CSR build: histogram / scan / scatter ids ----------------
__global__ __launch_bounds__(256) void hist_kernel(
    const int* __restrict__ edge_index, int* __restrict__ cnt)
{
    int stride = gridDim.x * blockDim.x;
    for (int e = blockIdx.x * blockDim.x + threadIdx.x; e < N_EDGES; e += stride)
        atomicAdd(&cnt[edge_index[N_EDGES + e]], 1);
}

__global__ __launch_bounds__(256) void scan_kernel(
    const int* __restrict__ cnt, int* __restrict__ base, int* __restrict__ cursor)
{
    __shared__ int part[256];
    int t = threadIdx.x;
    int lo = t * 40, hi = min(lo + 40, N_NODES);
    int s = 0;
    for (int i = lo; i < hi; ++i) s += cnt[i];
    part[t] = s;
    __syncthreads();
    if (t == 0) {
        int run = 0;
        for (int i = 0; i < 256; ++i) { int v = part[i]; part[i] = run; run += v; }
    }
    __syncthreads();
    int run = part[t];
    for (int i = lo; i < hi; ++i) {
        base[i] = run; cursor[i] = run; run += cnt[i];
    }
}

__global__ __launch_bounds__(256) void scatter_ids_kernel(
    const int* __restrict__ edge_index, int* __restrict__ cursor,
    int* __restrict__ sorted)
{
    int stride = gridDim.x * blockDim.x;
    for (int e = blockIdx.x * blockDim.x + threadIdx.x; e < N_EDGES; e += stride) {
        int d = edge_index[N_EDGES + e];
        int pos = atomicAdd(&cursor[d], 1);
        sorted[pos] = e;
    }
}

// ---------------- q = MLP_hq(h) ----------------
__global__ __launch_bounds__(128) void q_kernel(
    const float* __restrict__ h,
    const float* __restrict__ W1, const float* __restrict__ b1,
    const float* __restrict__ g1, const float* __restrict__ be1,
    const float* __restrict__ W2, const float* __restrict__ b2,
    float* __restrict__ qout)
{
    __shared__ __align__(16) float x[128];
    __shared__ __align__(16) float r[128];
    __shared__ float4 red4[2];
    int n = blockIdx.x, tid = threadIdx.x;
    x[tid] = h[(long)n * 128 + tid];
    __syncthreads();
    float y = b1[tid];
    #pragma unroll 4
    for (int i4 = 0; i4 < 128; i4 += 4) {
        float4 c = *(const float4*)&x[i4];
        y = fmaf(c.x, W1[(i4 + 0) * 128 + tid], y);
        y = fmaf(c.y, W1[(i4 + 1) * 128 + tid], y);
        y = fmaf(c.z, W1[(i4 + 2) * 128 + tid], y);
        y = fmaf(c.w, W1[(i4 + 3) * 128 + tid], y);
    }
    float4 s = make_float4(y, y * y, 0.f, 0.f);
    block_reduce4(s, red4);
    float mu  = s.x * 0.0078125f;
    float var = s.y * 0.0078125f - mu * mu;
    float ny = (y - mu) * rsqrtf(var + 1e-5f) * g1[tid] + be1[tid];
    r[tid] = fmaxf(ny, 0.f);
    __syncthreads();
    float y2 = b2[tid];
    #pragma unroll 4
    for (int i4 = 0; i4 < 128; i4 += 4) {
        float4 c = *(const float4*)&r[i4];
        y2 = fmaf(c.x, W2[(i4 + 0) * 128 + tid], y2);
        y2 = fmaf(c.y, W2[(i4 + 1) * 128 + tid], y2);
        y2 = fmaf(c.z, W2[(i4 + 2) * 128 + tid], y2);
        y2 = fmaf(c.w, W2[(i4 + 3) * 128 + tid], y2);
    }
    qout[(long)n * 128 + tid] = y2;
}

// ---------------- fused MFMA edge kernel ----------------
// 64 edges/block, 4 waves of 64. GEMM1: [64,352]x[352,256]; LN+ReLU; GEMM2: [64,128]x[128,256]
// LDS map (bytes):
//   0      .. 46080  : A1 bf16 [64][360]        (alias: A2 [64][264], then vbuf [64][136])
//   17408  .. 51200  : qbuf f32 [64][132]       (epilogue only; disjoint from vbuf)
//   51200  .. 71680  : Bt bf16 [256][40]
//   71680  .. 72704  : ln_s f32 [4][64]
//   72704  .. 73728  : ln_q f32 [4][64]
//   73728  .. 73984  : ew_s f32 [64]
//   73984  .. 74240  : dst_s int [64]
__global__ __launch_bounds__(256, 2) void edge_kernel(
    const float* __restrict__ h, const float* __restrict__ r_feat,
    const float* __restrict__ edge_feat, const int* __restrict__ edge_index,
    const short* __restrict__ Wt1, const short* __restrict__ Wt2,
    const float* __restrict__ kb1, const float* __restrict__ kg1,
    const float* __restrict__ kbe1, const float* __restrict__ kb2,
    const float* __restrict__ vb1, const float* __restrict__ vg1,
    const float* __restrict__ vbe1, const float* __restrict__ vb2,
    const float* __restrict__ ewW, const float* __restrict__ ewb,
    const float* __restrict__ q,
    float* __restrict__ logits_g, short* __restrict__ voutS)
{
    __shared__ __align__(16) char smem[74240];
    short* A1   = (short*)smem;                 // [64][360]
    short* A2   = (short*)smem;                 // [64][264]
    short* vbuf = (short*)smem;                 // [64][136]
    float* qbuf = (float*)(smem + 17408);       // [64][132]
    short* Bt   = (short*)(smem + 51200);       // [256][40]
    float* ln_s = (float*)(smem + 71680);       // [4][64]
    float* ln_q = (float*)(smem + 72704);       // [4][64]
    float* ew_s = (float*)(smem + 73728);       // [64]
    int*   dst_s= (int*)(smem + 73984);         // [64]

    const int tid  = threadIdx.x;
    const int w    = tid >> 6;          // wave 0..3
    const int lane = tid & 63;
    const int g    = lane >> 4;         // 0..3
    const int lr   = lane & 15;
    const int cw   = w * 64;            // this wave's output-col base (0..255)
    const long eg0 = (long)blockIdx.x * 64;

    // ---- stage A1 (gather + f32->bf16) : 4 lanes per row ----
    {
        int row = tid >> 2;             // 0..63
        int c4  = tid & 3;
        long eg = eg0 + row;
        int srcn = edge_index[eg];
        int dstn = edge_index[N_EDGES + eg];
        if (c4 == 0) dst_s[row] = dstn;
        short* arow = A1 + row * 360;
        if (c4 == 0) {
            float4 v = *(const float4*)&edge_feat[eg * 4];
            st_bf4(arow, v);
        }
        #pragma unroll
        for (int j = 0; j < 4; ++j) {
            float4 v = *(const float4*)&r_feat[eg * 64 + c4 * 16 + j * 4];
            st_bf4(arow + 4 + c4 * 16 + j * 4, v);
        }
        #pragma unroll
        for (int j = 0; j < 8; ++j) {
            float4 v = *(const float4*)&h[(size_t)dstn * 128 + c4 * 32 + j * 4];
            st_bf4(arow + 68 + c4 * 32 + j * 4, v);
        }
        #pragma unroll
        for (int j = 0; j < 8; ++j) {
            float4 v = *(const float4*)&h[(size_t)srcn * 128 + c4 * 32 + j * 4];
            st_bf4(arow + 196 + c4 * 32 + j * 4, v);
        }
        for (int gi = c4; gi < 9; gi += 4)
            *(int2*)(arow + 324 + gi * 4) = make_int2(0, 0);

        // e_w = sigmoid(r_feat . ewW + b)
        float p = 0.f;
        #pragma unroll
        for (int j = 0; j < 4; ++j) {
            float4 rv = *(const float4*)&r_feat[eg * 64 + c4 * 16 + j * 4];
            float4 wv = *(const float4*)&ewW[c4 * 16 + j * 4];
            p += rv.x * wv.x + rv.y * wv.y + rv.z * wv.z + rv.w * wv.w;
        }
        p += __shfl_xor(p, 1);
        p += __shfl_xor(p, 2);
        if (c4 == 0) ew_s[row] = 1.f / (1.f + expf(-(p + ewb[0])));
    }

    f32x4 acc[4][4];
    const f32x4 zero4 = {0.f, 0.f, 0.f, 0.f};
    #pragma unroll
    for (int mf = 0; mf < 4; ++mf)
        #pragma unroll
        for (int nf = 0; nf < 4; ++nf) acc[mf][nf] = zero4;

    // ---- GEMM1: K = 11 chunks of 32 ----
    #pragma unroll 1
    for (int ks = 0; ks < 11; ++ks) {
        __syncthreads();
        {
            const int4* src = (const int4*)(Wt1 + (size_t)ks * 10240);
            int4* dl = (int4*)Bt;
            #pragma unroll
            for (int i = 0; i < 5; ++i) dl[tid + i * 256] = src[tid + i * 256];
        }
        __syncthreads();
        bf16x8 bfr[4], afr[4];
        #pragma unroll
        for (int nf = 0; nf < 4; ++nf)
            bfr[nf] = *(const bf16x8*)&Bt[(cw + nf * 16 + lr) * 40 + g * 8];
        #pragma unroll
        for (int mf = 0; mf < 4; ++mf)
            afr[mf] = *(const bf16x8*)&A1[(mf * 16 + lr) * 360 + ks * 32 + g * 8];
        #pragma unroll
        for (int mf = 0; mf < 4; ++mf)
            #pragma unroll
            for (int nf = 0; nf < 4; ++nf)
                acc[mf][nf] = __builtin_amdgcn_mfma_f32_16x16x32_bf16(
                    afr[mf], bfr[nf], acc[mf][nf], 0, 0, 0);
    }

    // ---- bias + LayerNorm + ReLU -> A2 (bf16) ----
    const float* b1p  = (w < 2) ? kb1  : vb1;
    const float* g1p  = (w < 2) ? kg1  : vg1;
    const float* be1p = (w < 2) ? kbe1 : vbe1;
    const float* b2p  = (w < 2) ? kb2  : vb2;
    const int colm0 = cw & 127;
    float b1c[4], g1c[4], be1c[4], b2c[4];
    #pragma unroll
    for (int nf = 0; nf < 4; ++nf) {
        int cm = colm0 + nf * 16 + lr;
        b1c[nf] = b1p[cm]; g1c[nf] = g1p[cm]; be1c[nf] = be1p[cm]; b2c[nf] = b2p[cm];
    }
    float sum_[4][4], sq_[4][4];
    #pragma unroll
    for (int mf = 0; mf < 4; ++mf)
        #pragma unroll
        for (int r = 0; r < 4; ++r) { sum_[mf][r] = 0.f; sq_[mf][r] = 0.f; }
    #pragma unroll
    for (int mf = 0; mf < 4; ++mf)
        #pragma unroll
        for (int nf = 0; nf < 4; ++nf)
            #pragma unroll
            for (int r = 0; r < 4; ++r) {
                float a = acc[mf][nf][r] + b1c[nf];
                acc[mf][nf][r] = a;
                sum_[mf][r] += a;
                sq_[mf][r]  += a * a;
            }
    #pragma unroll
    for (int mf = 0; mf < 4; ++mf)
        #pragma unroll
        for (int r = 0; r < 4; ++r) {
            float s = sum_[mf][r], qq = sq_[mf][r];
            #pragma unroll
            for (int m = 1; m < 16; m <<= 1) {
                s  += __shfl_xor(s, m);
                qq += __shfl_xor(qq, m);
            }
            sum_[mf][r] = s; sq_[mf][r] = qq;
        }
    if (lr == 0) {
        #pragma unroll
        for (int mf = 0; mf < 4; ++mf)
            #pragma unroll
            for (int r = 0; r < 4; ++r) {
                int row = mf * 16 + g * 4 + r;
                ln_s[w * 64 + row] = sum_[mf][r];
                ln_q[w * 64 + row] = sq_[mf][r];
            }
    }
    __syncthreads();
    #pragma unroll
    for (int mf = 0; mf < 4; ++mf)
        #pragma unroll
        for (int r = 0; r < 4; ++r) {
            int row = mf * 16 + g * 4 + r;
            float mu  = (ln_s[w * 64 + row] + ln_s[(w ^ 1) * 64 + row]) * 0.0078125f;
            float ex2 = (ln_q[w * 64 + row] + ln_q[(w ^ 1) * 64 + row]) * 0.0078125f;
            float rs = rsqrtf(ex2 - mu * mu + 1e-5f);
            #pragma unroll
            for (int nf = 0; nf < 4; ++nf) {
                float nv = fmaxf((acc[mf][nf][r] - mu) * rs * g1c[nf] + be1c[nf], 0.f);
                A2[row * 264 + cw + nf * 16 + lr] = f2bf(nv);
            }
        }

    // ---- GEMM2: K = 4 chunks of 32 (waves 0,1: rk -> k-out; waves 2,3: rv -> v-out) ----
    #pragma unroll
    for (int mf = 0; mf < 4; ++mf)
        #pragma unroll
        for (int nf = 0; nf < 4; ++nf) acc[mf][nf] = zero4;
    const int kbase = (w < 2) ? 0 : 128;
    #pragma unroll 1
    for (int ks = 0; ks < 4; ++ks) {
        __syncthreads();
        {
            const int4* src = (const int4*)(Wt2 + (size_t)ks * 10240);
            int4* dl = (int4*)Bt;
            #pragma unroll
            for (int i = 0; i < 5; ++i) dl[tid + i * 256] = src[tid + i * 256];
        }
        __syncthreads();
        bf16x8 bfr[4], afr[4];
        #pragma unroll
        for (int nf = 0; nf < 4; ++nf)
            bfr[nf] = *(const bf16x8*)&Bt[(cw + nf * 16 + lr) * 40 + g * 8];
        #pragma unroll
        for (int mf = 0; mf < 4; ++mf)
            afr[mf] = *(const bf16x8*)&A2[(mf * 16 + lr) * 264 + kbase + ks * 32 + g * 8];
        #pragma unroll
        for (int mf = 0; mf < 4; ++mf)
            #pragma unroll
            for (int nf = 0; nf < 4; ++nf)
                acc[mf][nf] = __builtin_amdgcn_mfma_f32_16x16x32_bf16(
                    afr[mf], bfr[nf], acc[mf][nf], 0, 0, 0);
    }

    __syncthreads();   // GEMM2 done: A-region + Bt free

    // ---- stage q rows (f32) for logits ----
    {
        int row = tid >> 2, c4 = tid & 3;
        int dstn = dst_s[row];
        #pragma unroll
        for (int j = 0; j < 8; ++j)
            *(float4*)&qbuf[row * 132 + c4 * 32 + j * 4] =
                *(const float4*)&q[(size_t)dstn * 128 + c4 * 32 + j * 4];
    }
    // ---- waves 2,3: v2 = (acc + b2) * e_w -> vbuf bf16 ----
    if (w >= 2) {
        #pragma unroll
        for (int mf = 0; mf < 4; ++mf)
            #pragma unroll
            for (int r = 0; r < 4; ++r) {
                int row = mf * 16 + g * 4 + r;
                float ew = ew_s[row];
                #pragma unroll
                for (int nf = 0; nf < 4; ++nf) {
                    float vv = (acc[mf][nf][r] + b2c[nf]) * ew;
                    vbuf[row * 136 + (cw - 128) + nf * 16 + lr] = f2bf(vv);
                }
            }
    }
    __syncthreads();

    // ---- waves 0,1: logits ----
    if (w < 2) {
        #pragma unroll
        for (int mf = 0; mf < 4; ++mf)
            #pragma unroll
            for (int nf = 0; nf < 4; ++nf)
                #pragma unroll
                for (int r = 0; r < 4; ++r) {
                    int row = mf * 16 + g * 4 + r;
                    int col = cw + nf * 16 + lr;
                    float k2 = acc[mf][nf][r] + b2c[nf];
                    float p = k2 * qbuf[row * 132 + col];
                    p += __shfl_xor(p, 1);
                    p += __shfl_xor(p, 2);
                    p += __shfl_xor(p, 4);
                    if ((lane & 7) == 0) {
                        int head = col >> 3;
                        long eg = eg0 + row;
                        logits_g[eg * 16 + head] = p * 0.35355339059327373f;
                    }
                }
    }
    // ---- coalesced vout store: 64 rows x 128 bf16 = 1024 int4 ----
    #pragma unroll
    for (int i = tid; i < 1024; i += 256) {
        int row = i >> 4, p8 = i & 15;
        *(int4*)&voutS[(eg0 + row) * 128 + p8 * 8] = *(const int4*)&vbuf[row * 136 + p8 * 8];
    }
}

// ---------------- gather: per-dst softmax + weighted V sum (no float atomics) ----------------
__global__ __launch_bounds__(128) void gather_kernel(
    const int* __restrict__ base, const int* __restrict__ cnt,
    const int* __restrict__ sorted,
    const float* __restrict__ logits, const __hip_bfloat16* __restrict__ vout,
    float* __restrict__ msg)
{
    int d = blockIdx.x, t = threadIdx.x;
    int hd = t >> 3;
    int s = base[d], c = cnt[d];

    // phase 1: per-head max (8 lanes stride the edge list, then xor-reduce)
    float m = -3.402823466e+38f;
    for (int i = (t & 7); i < c; i += 8) {
        int e = sorted[s + i];
        m = fmaxf(m, logits[(long)e * 16 + hd]);
    }
    m = fmaxf(m, __shfl_xor(m, 1));
    m = fmaxf(m, __shfl_xor(m, 2));
    m = fmaxf(m, __shfl_xor(m, 4));

    // phase 2: accumulate exp-weighted v (each thread owns one output dim)
    float acc = 0.f, den = 0.f;
    for (int i = 0; i < c; ++i) {
        int e = sorted[s + i];
        float ex = expf(logits[(long)e * 16 + hd] - m);
        den += ex;
        acc += ex * __bfloat162float(vout[(long)e * 128 + t]);
    }
    msg[(long)d * 128 + t] = acc / (den + 1e-16f);
}

// ---------------- output MLP + residual ----------------
__global__ __launch_bounds__(128) void out_kernel(
    const float* __restrict__ h, const float* __restrict__ msg,
    const float* __restrict__ W1, const float* __restrict__ b1,
    const float* __restrict__ g1, const float* __restrict__ be1,
    const float* __restrict__ W2, const float* __restrict__ b2,
    float* __restrict__ out)
{
    __shared__ __align__(16) float xin[256];
    __shared__ __align__(16) float r[128];
    __shared__ float4 red4[2];
    int n = blockIdx.x, tid = threadIdx.x;
    float hval = h[(long)n * 128 + tid];
    xin[tid] = msg[(long)n * 128 + tid];
    xin[128 + tid] = hval;
    __syncthreads();
    float y = b1[tid];
    #pragma unroll 4
    for (int i4 = 0; i4 < 256; i4 += 4) {
        float4 c = *(const float4*)&xin[i4];
        y = fmaf(c.x, W1[(i4 + 0) * 128 + tid], y);
        y = fmaf(c.y, W1[(i4 + 1) * 128 + tid], y);
        y = fmaf(c.z, W1[(i4 + 2) * 128 + tid], y);
        y = fmaf(c.w, W1[(i4 + 3) * 128 + tid], y);
    }
    float4 s = make_float4(y, y * y, 0.f, 0.f);
    block_reduce4(s, red4);
    float mu  = s.x * 0.0078125f;
    float var = s.y * 0.0078125f - mu * mu;
    float ny = (y - mu) * rsqrtf(var + 1e-5f) * g1[tid] + be1[tid];
    r[tid] = fmaxf(ny, 0.f);
    __syncthreads();
    float y2 = b2[tid];
    #pragma unroll 4
    for (int i4 = 0; i4 < 128; i4 += 4) {
        float4 c = *(const float4*)&r[i4];
        y2 = fmaf(c.x, W2[(i4 + 0) * 128 + tid], y2);
        y2 = fmaf(c.y, W2[(i4 + 1) * 128 + tid], y2);
        y2 = fmaf(c.z, W2[(i4 + 2) * 128 + tid], y2);
        y2 = fmaf(c.w, W2[(i4 + 3) * 128 + tid], y2);
    }
    out[(long)n * 128 + tid] = y2 + hval;
}

// ---------------- host ----------------
extern "C" void kernel_launch(void* const* d_in, const int* in_sizes, int n_in,
                              void* d_out, int out_size, void* d_ws, size_t ws_size,
                              hipStream_t stream) {
    (void)in_sizes; (void)n_in; (void)out_size; (void)ws_size;
    const float* h         = (const float*)d_in[0];
    const float* r_feat    = (const float*)d_in[1];
    const float* edge_feat = (const float*)d_in[2];
    const int*   edge_index= (const int*)d_in[3];
    const float* kW1 = (const float*)d_in[4],  *kb1 = (const float*)d_in[5];
    const float* kg1 = (const float*)d_in[6],  *kbe1= (const float*)d_in[7];
    const float* kW2 = (const float*)d_in[8],  *kb2 = (const float*)d_in[9];
    const float* vW1 = (const float*)d_in[10], *vb1 = (const float*)d_in[11];
    const float* vg1 = (const float*)d_in[12], *vbe1= (const float*)d_in[13];
    const float* vW2 = (const float*)d_in[14], *vb2 = (const float*)d_in[15];
    const float* qW1 = (const float*)d_in[16], *qb1 = (const float*)d_in[17];
    const float* qg1 = (const float*)d_in[18], *qbe1= (const float*)d_in[19];
    const float* qW2 = (const float*)d_in[20], *qb2 = (const float*)d_in[21];
    const float* oW1 = (const float*)d_in[22], *ob1 = (const float*)d_in[23];
    const float* og1 = (const float*)d_in[24], *obe1= (const float*)d_in[25];
    const float* oW2 = (const float*)d_in[26], *ob2 = (const float*)d_in[27];
    const float* ewW = (const float*)d_in[28], *ewb = (const float*)d_in[29];
    float* out = (float*)d_out;

    char* ws = (char*)d_ws;
    float* q      = (float*)(ws);                     // [N,128] f32 ; aliased by msg after edge_kernel
    float* msg    = (float*)(ws);                     //   (gather writes after last q read)
    float* logits = (float*)(ws + 5120000);           // [E,16] f32
    short* voutS  = (short*)(ws + 25600000);          // [E,128] bf16
    short* Wt1    = (short*)(ws + 107520000);         // 225,280 B
    short* Wt2    = (short*)(ws + 107745280);         // 81,920 B
    int*   cnt    = (int*)(ws + 107827200);           // [N]
    int*   base   = (int*)(ws + 107867200);           // [N]
    int*   cursor = (int*)(ws + 107907200);           // [N]
    int*   sorted = (int*)(ws + 107947200);           // [E]

    hipMemsetAsync(cnt, 0, N_NODES * 4, stream);

    // CSR build (depends only on edge_index)
    hist_kernel<<<1250, 256, 0, stream>>>(edge_index, cnt);
    scan_kernel<<<1, 256, 0, stream>>>(cnt, base, cursor);
    scatter_ids_kernel<<<1250, 256, 0, stream>>>(edge_index, cursor, sorted);

    prep_wt_kernel<<<11, 256, 0, stream>>>(kW1, vW1, Wt1, 324);
    prep_wt_kernel<<<4, 256, 0, stream>>>(kW2, vW2, Wt2, 128);

    q_kernel<<<N_NODES, 128, 0, stream>>>(h, qW1, qb1, qg1, qbe1, qW2, qb2, q);

    edge_kernel<<<N_EDGES / 64, 256, 0, stream>>>(
        h, r_feat, edge_feat, edge_index, Wt1, Wt2,
        kb1, kg1, kbe1, kb2, vb1, vg1, vbe1, vb2,
        ewW, ewb, q, logits, voutS);

    gather_kernel<<<N_NODES, 128, 0, stream>>>(base, cnt, sorted, logits,
        (const __hip_bfloat16*)voutS, msg);

    out_kernel<<<N_NODES, 128, 0, stream>>>(h, msg, oW1, ob1, og1, obe1, oW2, ob2, out);
}

// Round 9
// 656.241 us; speedup vs baseline: 5.7121x; 1.1322x over previous
//
#include <hip/hip_runtime.h>
#include <hip/hip_bf16.h>

#define N_NODES 10000
#define N_EDGES 320000

typedef __attribute__((ext_vector_type(8))) short bf16x8;
typedef __attribute__((ext_vector_type(4))) float f32x4;

__device__ inline short f2bf(float x) {
    __hip_bfloat16 h = __float2bfloat16(x);
    union { __hip_bfloat16 h; short s; } u; u.h = h; return u.s;
}

__device__ inline void st_bf4(short* p, float4 v) {
    union { short s[4]; int2 i; } u;
    u.s[0] = f2bf(v.x); u.s[1] = f2bf(v.y); u.s[2] = f2bf(v.z); u.s[3] = f2bf(v.w);
    *(int2*)p = u.i;
}

__device__ inline void block_reduce4(float4& v, float4* red) {
    #pragma unroll
    for (int o = 32; o > 0; o >>= 1) {
        v.x += __shfl_down(v.x, o, 64);
        v.y += __shfl_down(v.y, o, 64);
        v.z += __shfl_down(v.z, o, 64);
        v.w += __shfl_down(v.w, o, 64);
    }
    __syncthreads();
    if ((threadIdx.x & 63) == 0) red[threadIdx.x >> 6] = v;
    __syncthreads();
    float4 a = red[0], b = red[1];
    v.x = a.x + b.x; v.y = a.y + b.y; v.z = a.z + b.z; v.w = a.w + b.w;
}

// ---------------- weight prep: [nch][256 cols][32 k] bf16 (fragment-ordered, dense) ----------------
__global__ __launch_bounds__(256) void prep_wt_kernel(
    const float* __restrict__ Wk, const float* __restrict__ Wv,
    short* __restrict__ Wt, int K)
{
    int col = threadIdx.x, ch = blockIdx.x;
    const float* W = (col < 128) ? Wk : Wv;
    int c = col & 127;
    short tmp[32];
    #pragma unroll
    for (int kk = 0; kk < 32; ++kk) {
        int k = ch * 32 + kk;
        float w = (k < K) ? W[k * 128 + c] : 0.f;
        tmp[kk] = f2bf(w);
    }
    short* outp = Wt + ((size_t)ch * 256 + col) * 32;
    #pragma unroll
    for (int i = 0; i < 4; ++i) {
        union { short s[8]; int4 v; } u;
        #pragma unroll
        for (int j = 0; j < 8; ++j) u.s[j] = tmp[i * 8 + j];
        *(int4*)(outp + i * 8) = u.v;
    }
}

// ---------------- CSR build: histogram / scan / scatter ids ----------------
__global__ __launch_bounds__(256) void hist_kernel(
    const int* __restrict__ edge_index, int* __restrict__ cnt)
{
    int stride = gridDim.x * blockDim.x;
    for (int e = blockIdx.x * blockDim.x + threadIdx.x; e < N_EDGES; e += stride)
        atomicAdd(&cnt[edge_index[N_EDGES + e]], 1);
}

__global__ __launch_bounds__(256) void scan_kernel(
    const int* __restrict__ cnt, int* __restrict__ base, int* __restrict__ cursor)
{
    __shared__ int part[256];
    int t = threadIdx.x;
    int lo = t * 40, hi = min(lo + 40, N_NODES);
    int s = 0;
    for (int i = lo; i < hi; ++i) s += cnt[i];
    part[t] = s;
    __syncthreads();
    if (t == 0) {
        int run = 0;
        for (int i = 0; i < 256; ++i) { int v = part[i]; part[i] = run; run += v; }
    }
    __syncthreads();
    int run = part[t];
    for (int i = lo; i < hi; ++i) {
        base[i] = run; cursor[i] = run; run += cnt[i];
    }
}

__global__ __launch_bounds__(256) void scatter_ids_kernel(
    const int* __restrict__ edge_index, int* __restrict__ cursor,
    int* __restrict__ sorted)
{
    int stride = gridDim.x * blockDim.x;
    for (int e = blockIdx.x * blockDim.x + threadIdx.x; e < N_EDGES; e += stride) {
        int d = edge_index[N_EDGES + e];
        int pos = atomicAdd(&cursor[d], 1);
        sorted[pos] = e;
    }
}

// ---------------- q = MLP_hq(h) ----------------
__global__ __launch_bounds__(128) void q_kernel(
    const float* __restrict__ h,
    const float* __restrict__ W1, const float* __restrict__ b1,
    const float* __restrict__ g1, const float* __restrict__ be1,
    const float* __restrict__ W2, const float* __restrict__ b2,
    float* __restrict__ qout)
{
    __shared__ __align__(16) float x[128];
    __shared__ __align__(16) float r[128];
    __shared__ float4 red4[2];
    int n = blockIdx.x, tid = threadIdx.x;
    x[tid] = h[(long)n * 128 + tid];
    __syncthreads();
    float y = b1[tid];
    #pragma unroll 4
    for (int i4 = 0; i4 < 128; i4 += 4) {
        float4 c = *(const float4*)&x[i4];
        y = fmaf(c.x, W1[(i4 + 0) * 128 + tid], y);
        y = fmaf(c.y, W1[(i4 + 1) * 128 + tid], y);
        y = fmaf(c.z, W1[(i4 + 2) * 128 + tid], y);
        y = fmaf(c.w, W1[(i4 + 3) * 128 + tid], y);
    }
    float4 s = make_float4(y, y * y, 0.f, 0.f);
    block_reduce4(s, red4);
    float mu  = s.x * 0.0078125f;
    float var = s.y * 0.0078125f - mu * mu;
    float ny = (y - mu) * rsqrtf(var + 1e-5f) * g1[tid] + be1[tid];
    r[tid] = fmaxf(ny, 0.f);
    __syncthreads();
    float y2 = b2[tid];
    #pragma unroll 4
    for (int i4 = 0; i4 < 128; i4 += 4) {
        float4 c = *(const float4*)&r[i4];
        y2 = fmaf(c.x, W2[(i4 + 0) * 128 + tid], y2);
        y2 = fmaf(c.y, W2[(i4 + 1) * 128 + tid], y2);
        y2 = fmaf(c.z, W2[(i4 + 2) * 128 + tid], y2);
        y2 = fmaf(c.w, W2[(i4 + 3) * 128 + tid], y2);
    }
    qout[(long)n * 128 + tid] = y2;
}

// ---------------- fused MFMA edge kernel (B direct from global, barrier-light) ----------------
// 64 edges/block, 4 waves. GEMM1: [64,352]x[352,256]; LN+ReLU; GEMM2: [64,128]x[128,256]
// B fragments are loaded global->VGPR from the fragment-ordered Wt buffers (L2-resident);
// no Bt LDS staging, no per-chunk barriers. 5 barriers/block total.
// LDS map (bytes), total 53760 -> 3 blocks/CU:
//   0      .. 46080 : A1 bf16 [64][360]   (alias: A2 [64][264], then vbuf [64][136])
//   17408  .. 51200 : qbuf f32 [64][132]  (epilogue only; disjoint from vbuf)
//   51200  .. 52224 : ln_s f32 [4][64]
//   52224  .. 53248 : ln_q f32 [4][64]
//   53248  .. 53504 : ew_s f32 [64]
//   53504  .. 53760 : dst_s int [64]
__global__ __launch_bounds__(256, 3) void edge_kernel(
    const float* __restrict__ h, const float* __restrict__ r_feat,
    const float* __restrict__ edge_feat, const int* __restrict__ edge_index,
    const short* __restrict__ Wt1, const short* __restrict__ Wt2,
    const float* __restrict__ kb1, const float* __restrict__ kg1,
    const float* __restrict__ kbe1, const float* __restrict__ kb2,
    const float* __restrict__ vb1, const float* __restrict__ vg1,
    const float* __restrict__ vbe1, const float* __restrict__ vb2,
    const float* __restrict__ ewW, const float* __restrict__ ewb,
    const float* __restrict__ q,
    float* __restrict__ logits_g, short* __restrict__ voutS)
{
    __shared__ __align__(16) char smem[53760];
    short* A1   = (short*)smem;                 // [64][360]
    short* A2   = (short*)smem;                 // [64][264]
    short* vbuf = (short*)smem;                 // [64][136]
    float* qbuf = (float*)(smem + 17408);       // [64][132]
    float* ln_s = (float*)(smem + 51200);       // [4][64]
    float* ln_q = (float*)(smem + 52224);       // [4][64]
    float* ew_s = (float*)(smem + 53248);       // [64]
    int*   dst_s= (int*)(smem + 53504);         // [64]

    const int tid  = threadIdx.x;
    const int w    = tid >> 6;          // wave 0..3
    const int lane = tid & 63;
    const int g    = lane >> 4;         // 0..3
    const int lr   = lane & 15;
    const int cw   = w * 64;            // this wave's output-col base (0..255)
    const long eg0 = (long)blockIdx.x * 64;

    // ---- stage A1 (gather + f32->bf16) : 4 lanes per row ----
    {
        int row = tid >> 2;             // 0..63
        int c4  = tid & 3;
        long eg = eg0 + row;
        int srcn = edge_index[eg];
        int dstn = edge_index[N_EDGES + eg];
        if (c4 == 0) dst_s[row] = dstn;
        short* arow = A1 + row * 360;
        if (c4 == 0) {
            float4 v = *(const float4*)&edge_feat[eg * 4];
            st_bf4(arow, v);
        }
        #pragma unroll
        for (int j = 0; j < 4; ++j) {
            float4 v = *(const float4*)&r_feat[eg * 64 + c4 * 16 + j * 4];
            st_bf4(arow + 4 + c4 * 16 + j * 4, v);
        }
        #pragma unroll
        for (int j = 0; j < 8; ++j) {
            float4 v = *(const float4*)&h[(size_t)dstn * 128 + c4 * 32 + j * 4];
            st_bf4(arow + 68 + c4 * 32 + j * 4, v);
        }
        #pragma unroll
        for (int j = 0; j < 8; ++j) {
            float4 v = *(const float4*)&h[(size_t)srcn * 128 + c4 * 32 + j * 4];
            st_bf4(arow + 196 + c4 * 32 + j * 4, v);
        }
        for (int gi = c4; gi < 9; gi += 4)
            *(int2*)(arow + 324 + gi * 4) = make_int2(0, 0);

        // e_w = sigmoid(r_feat . ewW + b)
        float p = 0.f;
        #pragma unroll
        for (int j = 0; j < 4; ++j) {
            float4 rv = *(const float4*)&r_feat[eg * 64 + c4 * 16 + j * 4];
            float4 wv = *(const float4*)&ewW[c4 * 16 + j * 4];
            p += rv.x * wv.x + rv.y * wv.y + rv.z * wv.z + rv.w * wv.w;
        }
        p += __shfl_xor(p, 1);
        p += __shfl_xor(p, 2);
        if (c4 == 0) ew_s[row] = 1.f / (1.f + expf(-(p + ewb[0])));
    }
    __syncthreads();   // barrier 1: A1 / ew_s / dst_s ready

    f32x4 acc[4][4];
    const f32x4 zero4 = {0.f, 0.f, 0.f, 0.f};
    #pragma unroll
    for (int mf = 0; mf < 4; ++mf)
        #pragma unroll
        for (int nf = 0; nf < 4; ++nf) acc[mf][nf] = zero4;

    // ---- GEMM1: K = 11 chunks of 32, B fragments straight from global (L2) ----
    #pragma unroll 2
    for (int ks = 0; ks < 11; ++ks) {
        bf16x8 bfr[4], afr[4];
        const short* wb = Wt1 + (size_t)ks * 8192 + (cw + lr) * 32 + g * 8;
        #pragma unroll
        for (int nf = 0; nf < 4; ++nf)
            bfr[nf] = *(const bf16x8*)(wb + nf * 512);
        #pragma unroll
        for (int mf = 0; mf < 4; ++mf)
            afr[mf] = *(const bf16x8*)&A1[(mf * 16 + lr) * 360 + ks * 32 + g * 8];
        #pragma unroll
        for (int mf = 0; mf < 4; ++mf)
            #pragma unroll
            for (int nf = 0; nf < 4; ++nf)
                acc[mf][nf] = __builtin_amdgcn_mfma_f32_16x16x32_bf16(
                    afr[mf], bfr[nf], acc[mf][nf], 0, 0, 0);
    }

    // ---- bias + LayerNorm + ReLU -> A2 (bf16) ----
    const float* b1p  = (w < 2) ? kb1  : vb1;
    const float* g1p  = (w < 2) ? kg1  : vg1;
    const float* be1p = (w < 2) ? kbe1 : vbe1;
    const float* b2p  = (w < 2) ? kb2  : vb2;
    const int colm0 = cw & 127;
    float b1c[4], g1c[4], be1c[4], b2c[4];
    #pragma unroll
    for (int nf = 0; nf < 4; ++nf) {
        int cm = colm0 + nf * 16 + lr;
        b1c[nf] = b1p[cm]; g1c[nf] = g1p[cm]; be1c[nf] = be1p[cm]; b2c[nf] = b2p[cm];
    }
    float sum_[4][4], sq_[4][4];
    #pragma unroll
    for (int mf = 0; mf < 4; ++mf)
        #pragma unroll
        for (int r = 0; r < 4; ++r) { sum_[mf][r] = 0.f; sq_[mf][r] = 0.f; }
    #pragma unroll
    for (int mf = 0; mf < 4; ++mf)
        #pragma unroll
        for (int nf = 0; nf < 4; ++nf)
            #pragma unroll
            for (int r = 0; r < 4; ++r) {
                float a = acc[mf][nf][r] + b1c[nf];
                acc[mf][nf][r] = a;
                sum_[mf][r] += a;
                sq_[mf][r]  += a * a;
            }
    #pragma unroll
    for (int mf = 0; mf < 4; ++mf)
        #pragma unroll
        for (int r = 0; r < 4; ++r) {
            float s = sum_[mf][r], qq = sq_[mf][r];
            #pragma unroll
            for (int m = 1; m < 16; m <<= 1) {
                s  += __shfl_xor(s, m);
                qq += __shfl_xor(qq, m);
            }
            sum_[mf][r] = s; sq_[mf][r] = qq;
        }
    if (lr == 0) {
        #pragma unroll
        for (int mf = 0; mf < 4; ++mf)
            #pragma unroll
            for (int r = 0; r < 4; ++r) {
                int row = mf * 16 + g * 4 + r;
                ln_s[w * 64 + row] = sum_[mf][r];
                ln_q[w * 64 + row] = sq_[mf][r];
            }
    }
    __syncthreads();   // barrier 2: ln partials ready
    #pragma unroll
    for (int mf = 0; mf < 4; ++mf)
        #pragma unroll
        for (int r = 0; r < 4; ++r) {
            int row = mf * 16 + g * 4 + r;
            float mu  = (ln_s[w * 64 + row] + ln_s[(w ^ 1) * 64 + row]) * 0.0078125f;
            float ex2 = (ln_q[w * 64 + row] + ln_q[(w ^ 1) * 64 + row]) * 0.0078125f;
            float rs = rsqrtf(ex2 - mu * mu + 1e-5f);
            #pragma unroll
            for (int nf = 0; nf < 4; ++nf) {
                float nv = fmaxf((acc[mf][nf][r] - mu) * rs * g1c[nf] + be1c[nf], 0.f);
                A2[row * 264 + cw + nf * 16 + lr] = f2bf(nv);
            }
        }
    __syncthreads();   // barrier 3: A2 ready

    // ---- GEMM2: K = 4 chunks of 32 (waves 0,1: k-out; waves 2,3: v-out) ----
    #pragma unroll
    for (int mf = 0; mf < 4; ++mf)
        #pragma unroll
        for (int nf = 0; nf < 4; ++nf) acc[mf][nf] = zero4;
    const int kbase = (w < 2) ? 0 : 128;
    #pragma unroll 2
    for (int ks = 0; ks < 4; ++ks) {
        bf16x8 bfr[4], afr[4];
        const short* wb = Wt2 + (size_t)ks * 8192 + (cw + lr) * 32 + g * 8;
        #pragma unroll
        for (int nf = 0; nf < 4; ++nf)
            bfr[nf] = *(const bf16x8*)(wb + nf * 512);
        #pragma unroll
        for (int mf = 0; mf < 4; ++mf)
            afr[mf] = *(const bf16x8*)&A2[(mf * 16 + lr) * 264 + kbase + ks * 32 + g * 8];
        #pragma unroll
        for (int mf = 0; mf < 4; ++mf)
            #pragma unroll
            for (int nf = 0; nf < 4; ++nf)
                acc[mf][nf] = __builtin_amdgcn_mfma_f32_16x16x32_bf16(
                    afr[mf], bfr[nf], acc[mf][nf], 0, 0, 0);
    }
    __syncthreads();   // barrier 4: GEMM2 done, A-region free for vbuf/qbuf overlay

    // ---- stage q rows (f32) for logits ----
    {
        int row = tid >> 2, c4 = tid & 3;
        int dstn = dst_s[row];
        #pragma unroll
        for (int j = 0; j < 8; ++j)
            *(float4*)&qbuf[row * 132 + c4 * 32 + j * 4] =
                *(const float4*)&q[(size_t)dstn * 128 + c4 * 32 + j * 4];
    }
    // ---- waves 2,3: v2 = (acc + b2) * e_w -> vbuf bf16 ----
    if (w >= 2) {
        #pragma unroll
        for (int mf = 0; mf < 4; ++mf)
            #pragma unroll
            for (int r = 0; r < 4; ++r) {
                int row = mf * 16 + g * 4 + r;
                float ew = ew_s[row];
                #pragma unroll
                for (int nf = 0; nf < 4; ++nf) {
                    float vv = (acc[mf][nf][r] + b2c[nf]) * ew;
                    vbuf[row * 136 + (cw - 128) + nf * 16 + lr] = f2bf(vv);
                }
            }
    }
    __syncthreads();   // barrier 5: vbuf + qbuf ready

    // ---- waves 0,1: logits ----
    if (w < 2) {
        #pragma unroll
        for (int mf = 0; mf < 4; ++mf)
            #pragma unroll
            for (int nf = 0; nf < 4; ++nf)
                #pragma unroll
                for (int r = 0; r < 4; ++r) {
                    int row = mf * 16 + g * 4 + r;
                    int col = cw + nf * 16 + lr;
                    float k2 = acc[mf][nf][r] + b2c[nf];
                    float p = k2 * qbuf[row * 132 + col];
                    p += __shfl_xor(p, 1);
                    p += __shfl_xor(p, 2);
                    p += __shfl_xor(p, 4);
                    if ((lane & 7) == 0) {
                        int head = col >> 3;
                        long eg = eg0 + row;
                        logits_g[eg * 16 + head] = p * 0.35355339059327373f;
                    }
                }
    }
    // ---- coalesced vout store: 64 rows x 128 bf16 = 1024 int4 ----
    #pragma unroll
    for (int i = tid; i < 1024; i += 256) {
        int row = i >> 4, p8 = i & 15;
        *(int4*)&voutS[(eg0 + row) * 128 + p8 * 8] = *(const int4*)&vbuf[row * 136 + p8 * 8];
    }
}

// ---------------- gather: per-dst softmax + weighted V sum (no float atomics) ----------------
__global__ __launch_bounds__(128) void gather_kernel(
    const int* __restrict__ base, const int* __restrict__ cnt,
    const int* __restrict__ sorted,
    const float* __restrict__ logits, const __hip_bfloat16* __restrict__ vout,
    float* __restrict__ msg)
{
    int d = blockIdx.x, t = threadIdx.x;
    int hd = t >> 3;
    int s = base[d], c = cnt[d];

    // phase 1: per-head max (8 lanes stride the edge list, then xor-reduce)
    float m = -3.402823466e+38f;
    for (int i = (t & 7); i < c; i += 8) {
        int e = sorted[s + i];
        m = fmaxf(m, logits[(long)e * 16 + hd]);
    }
    m = fmaxf(m, __shfl_xor(m, 1));
    m = fmaxf(m, __shfl_xor(m, 2));
    m = fmaxf(m, __shfl_xor(m, 4));

    // phase 2: accumulate exp-weighted v (each thread owns one output dim)
    float acc = 0.f, den = 0.f;
    for (int i = 0; i < c; ++i) {
        int e = sorted[s + i];
        float ex = expf(logits[(long)e * 16 + hd] - m);
        den += ex;
        acc += ex * __bfloat162float(vout[(long)e * 128 + t]);
    }
    msg[(long)d * 128 + t] = acc / (den + 1e-16f);
}

// ---------------- output MLP + residual ----------------
__global__ __launch_bounds__(128) void out_kernel(
    const float* __restrict__ h, const float* __restrict__ msg,
    const float* __restrict__ W1, const float* __restrict__ b1,
    const float* __restrict__ g1, const float* __restrict__ be1,
    const float* __restrict__ W2, const float* __restrict__ b2,
    float* __restrict__ out)
{
    __shared__ __align__(16) float xin[256];
    __shared__ __align__(16) float r[128];
    __shared__ float4 red4[2];
    int n = blockIdx.x, tid = threadIdx.x;
    float hval = h[(long)n * 128 + tid];
    xin[tid] = msg[(long)n * 128 + tid];
    xin[128 + tid] = hval;
    __syncthreads();
    float y = b1[tid];
    #pragma unroll 4
    for (int i4 = 0; i4 < 256; i4 += 4) {
        float4 c = *(const float4*)&xin[i4];
        y = fmaf(c.x, W1[(i4 + 0) * 128 + tid], y);
        y = fmaf(c.y, W1[(i4 + 1) * 128 + tid], y);
        y = fmaf(c.z, W1[(i4 + 2) * 128 + tid], y);
        y = fmaf(c.w, W1[(i4 + 3) * 128 + tid], y);
    }
    float4 s = make_float4(y, y * y, 0.f, 0.f);
    block_reduce4(s, red4);
    float mu  = s.x * 0.0078125f;
    float var = s.y * 0.0078125f - mu * mu;
    float ny = (y - mu) * rsqrtf(var + 1e-5f) * g1[tid] + be1[tid];
    r[tid] = fmaxf(ny, 0.f);
    __syncthreads();
    float y2 = b2[tid];
    #pragma unroll 4
    for (int i4 = 0; i4 < 128; i4 += 4) {
        float4 c = *(const float4*)&r[i4];
        y2 = fmaf(c.x, W2[(i4 + 0) * 128 + tid], y2);
        y2 = fmaf(c.y, W2[(i4 + 1) * 128 + tid], y2);
        y2 = fmaf(c.z, W2[(i4 + 2) * 128 + tid], y2);
        y2 = fmaf(c.w, W2[(i4 + 3) * 128 + tid], y2);
    }
    out[(long)n * 128 + tid] = y2 + hval;
}

// ---------------- host ----------------
extern "C" void kernel_launch(void* const* d_in, const int* in_sizes, int n_in,
                              void* d_out, int out_size, void* d_ws, size_t ws_size,
                              hipStream_t stream) {
    (void)in_sizes; (void)n_in; (void)out_size; (void)ws_size;
    const float* h         = (const float*)d_in[0];
    const float* r_feat    = (const float*)d_in[1];
    const float* edge_feat = (const float*)d_in[2];
    const int*   edge_index= (const int*)d_in[3];
    const float* kW1 = (const float*)d_in[4],  *kb1 = (const float*)d_in[5];
    const float* kg1 = (const float*)d_in[6],  *kbe1= (const float*)d_in[7];
    const float* kW2 = (const float*)d_in[8],  *kb2 = (const float*)d_in[9];
    const float* vW1 = (const float*)d_in[10], *vb1 = (const float*)d_in[11];
    const float* vg1 = (const float*)d_in[12], *vbe1= (const float*)d_in[13];
    const float* vW2 = (const float*)d_in[14], *vb2 = (const float*)d_in[15];
    const float* qW1 = (const float*)d_in[16], *qb1 = (const float*)d_in[17];
    const float* qg1 = (const float*)d_in[18], *qbe1= (const float*)d_in[19];
    const float* qW2 = (const float*)d_in[20], *qb2 = (const float*)d_in[21];
    const float* oW1 = (const float*)d_in[22], *ob1 = (const float*)d_in[23];
    const float* og1 = (const float*)d_in[24], *obe1= (const float*)d_in[25];
    const float* oW2 = (const float*)d_in[26], *ob2 = (const float*)d_in[27];
    const float* ewW = (const float*)d_in[28], *ewb = (const float*)d_in[29];
    float* out = (float*)d_out;

    char* ws = (char*)d_ws;
    float* q      = (float*)(ws);                     // [N,128] f32 ; aliased by msg after edge_kernel
    float* msg    = (float*)(ws);                     //   (gather writes after last q read)
    float* logits = (float*)(ws + 5120000);           // [E,16] f32
    short* voutS  = (short*)(ws + 25600000);          // [E,128] bf16
    short* Wt1    = (short*)(ws + 107520000);         // 11*256*32*2 = 180,224 B
    short* Wt2    = (short*)(ws + 107700224);         // 4*256*32*2  =  65,536 B
    int*   cnt    = (int*)(ws + 107765760);           // [N]
    int*   base   = (int*)(ws + 107805760);           // [N]
    int*   cursor = (int*)(ws + 107845760);           // [N]
    int*   sorted = (int*)(ws + 107885760);           // [E]

    hipMemsetAsync(cnt, 0, N_NODES * 4, stream);

    // CSR build (depends only on edge_index)
    hist_kernel<<<1250, 256, 0, stream>>>(edge_index, cnt);
    scan_kernel<<<1, 256, 0, stream>>>(cnt, base, cursor);
    scatter_ids_kernel<<<1250, 256, 0, stream>>>(edge_index, cursor, sorted);

    prep_wt_kernel<<<11, 256, 0, stream>>>(kW1, vW1, Wt1, 324);
    prep_wt_kernel<<<4, 256, 0, stream>>>(kW2, vW2, Wt2, 128);

    q_kernel<<<N_NODES, 128, 0, stream>>>(h, qW1, qb1, qg1, qbe1, qW2, qb2, q);

    edge_kernel<<<N_EDGES / 64, 256, 0, stream>>>(
        h, r_feat, edge_feat, edge_index, Wt1, Wt2,
        kb1, kg1, kbe1, kb2, vb1, vg1, vbe1, vb2,
        ewW, ewb, q, logits, voutS);

    gather_kernel<<<N_NODES, 128, 0, stream>>>(base, cnt, sorted, logits,
        (const __hip_bfloat16*)voutS, msg);

    out_kernel<<<N_NODES, 128, 0, stream>>>(h, msg, oW1, ob1, og1, obe1, oW2, ob2, out);
}

// Round 12
// 598.659 us; speedup vs baseline: 6.2615x; 1.0962x over previous
//
#include <hip/hip_runtime.h>
#include <hip/hip_bf16.h>

#define N_NODES 10000
#define N_EDGES 320000

typedef __attribute__((ext_vector_type(8))) short bf16x8;
typedef __attribute__((ext_vector_type(4))) float f32x4;

__device__ inline short f2bf(float x) {
    __hip_bfloat16 h = __float2bfloat16(x);
    union { __hip_bfloat16 h; short s; } u; u.h = h; return u.s;
}

__device__ inline void st_bf4(short* p, float4 v) {
    union { short s[4]; int2 i; } u;
    u.s[0] = f2bf(v.x); u.s[1] = f2bf(v.y); u.s[2] = f2bf(v.z); u.s[3] = f2bf(v.w);
    *(int2*)p = u.i;
}

__device__ inline void block_reduce4(float4& v, float4* red) {
    #pragma unroll
    for (int o = 32; o > 0; o >>= 1) {
        v.x += __shfl_down(v.x, o, 64);
        v.y += __shfl_down(v.y, o, 64);
        v.z += __shfl_down(v.z, o, 64);
        v.w += __shfl_down(v.w, o, 64);
    }
    __syncthreads();
    if ((threadIdx.x & 63) == 0) red[threadIdx.x >> 6] = v;
    __syncthreads();
    float4 a = red[0], b = red[1];
    v.x = a.x + b.x; v.y = a.y + b.y; v.z = a.z + b.z; v.w = a.w + b.w;
}

// ---------------- weight prep: [nch][256 cols][32 k] bf16 (fragment-ordered, dense) ----------------
__global__ __launch_bounds__(256) void prep_wt_kernel(
    const float* __restrict__ Wk, const float* __restrict__ Wv,
    short* __restrict__ Wt, int K)
{
    int col = threadIdx.x, ch = blockIdx.x;
    const float* W = (col < 128) ? Wk : Wv;
    int c = col & 127;
    short tmp[32];
    #pragma unroll
    for (int kk = 0; kk < 32; ++kk) {
        int k = ch * 32 + kk;
        float w = (k < K) ? W[k * 128 + c] : 0.f;
        tmp[kk] = f2bf(w);
    }
    short* outp = Wt + ((size_t)ch * 256 + col) * 32;
    #pragma unroll
    for (int i = 0; i < 4; ++i) {
        union { short s[8]; int4 v; } u;
        #pragma unroll
        for (int j = 0; j < 8; ++j) u.s[j] = tmp[i * 8 + j];
        *(int4*)(outp + i * 8) = u.v;
    }
}

// ---------------- CSR build: histogram / scan / scatter ids ----------------
__global__ __launch_bounds__(256) void hist_kernel(
    const int* __restrict__ edge_index, int* __restrict__ cnt)
{
    int stride = gridDim.x * blockDim.x;
    for (int e = blockIdx.x * blockDim.x + threadIdx.x; e < N_EDGES; e += stride)
        atomicAdd(&cnt[edge_index[N_EDGES + e]], 1);
}

__global__ __launch_bounds__(256) void scan_kernel(
    const int* __restrict__ cnt, int* __restrict__ base, int* __restrict__ cursor)
{
    __shared__ int part[256];
    int t = threadIdx.x;
    int lo = t * 40, hi = min(lo + 40, N_NODES);
    int s = 0;
    for (int i = lo; i < hi; ++i) s += cnt[i];
    part[t] = s;
    __syncthreads();
    if (t == 0) {
        int run = 0;
        for (int i = 0; i < 256; ++i) { int v = part[i]; part[i] = run; run += v; }
    }
    __syncthreads();
    int run = part[t];
    for (int i = lo; i < hi; ++i) {
        base[i] = run; cursor[i] = run; run += cnt[i];
    }
}

__global__ __launch_bounds__(256) void scatter_ids_kernel(
    const int* __restrict__ edge_index, int* __restrict__ cursor,
    int* __restrict__ sorted)
{
    int stride = gridDim.x * blockDim.x;
    for (int e = blockIdx.x * blockDim.x + threadIdx.x; e < N_EDGES; e += stride) {
        int d = edge_index[N_EDGES + e];
        int pos = atomicAdd(&cursor[d], 1);
        sorted[pos] = e;
    }
}

// ---------------- q = MLP_hq(h), 8 nodes/block (weights reused in regs) ----------------
__global__ __launch_bounds__(128) void q_kernel(
    const float* __restrict__ h,
    const float* __restrict__ W1, const float* __restrict__ b1,
    const float* __restrict__ g1, const float* __restrict__ be1,
    const float* __restrict__ W2, const float* __restrict__ b2,
    float* __restrict__ qout)
{
    __shared__ __align__(16) float xs[8][128];
    __shared__ __align__(16) float rs[8][128];
    __shared__ float4 red4[2];
    int n0 = blockIdx.x * 8, tid = threadIdx.x;
    #pragma unroll
    for (int n = 0; n < 8; ++n)
        xs[n][tid] = h[(long)(n0 + n) * 128 + tid];
    __syncthreads();
    float y[8];
    {
        float b = b1[tid];
        #pragma unroll
        for (int n = 0; n < 8; ++n) y[n] = b;
    }
    for (int i4 = 0; i4 < 128; i4 += 4) {
        float w0 = W1[(i4 + 0) * 128 + tid], w1 = W1[(i4 + 1) * 128 + tid];
        float w2 = W1[(i4 + 2) * 128 + tid], w3 = W1[(i4 + 3) * 128 + tid];
        #pragma unroll
        for (int n = 0; n < 8; ++n) {
            float4 c = *(const float4*)&xs[n][i4];
            y[n] = fmaf(c.x, w0, y[n]); y[n] = fmaf(c.y, w1, y[n]);
            y[n] = fmaf(c.z, w2, y[n]); y[n] = fmaf(c.w, w3, y[n]);
        }
    }
    float gv = g1[tid], bev = be1[tid];
    #pragma unroll 1
    for (int p = 0; p < 4; ++p) {
        int na = 2 * p, nb = 2 * p + 1;
        float4 s = make_float4(y[na], y[na] * y[na], y[nb], y[nb] * y[nb]);
        block_reduce4(s, red4);
        float muA = s.x * 0.0078125f, vA = s.y * 0.0078125f - muA * muA;
        float muB = s.z * 0.0078125f, vB = s.w * 0.0078125f - muB * muB;
        rs[na][tid] = fmaxf((y[na] - muA) * rsqrtf(vA + 1e-5f) * gv + bev, 0.f);
        rs[nb][tid] = fmaxf((y[nb] - muB) * rsqrtf(vB + 1e-5f) * gv + bev, 0.f);
    }
    __syncthreads();
    float y2[8];
    {
        float b = b2[tid];
        #pragma unroll
        for (int n = 0; n < 8; ++n) y2[n] = b;
    }
    for (int i4 = 0; i4 < 128; i4 += 4) {
        float w0 = W2[(i4 + 0) * 128 + tid], w1 = W2[(i4 + 1) * 128 + tid];
        float w2 = W2[(i4 + 2) * 128 + tid], w3 = W2[(i4 + 3) * 128 + tid];
        #pragma unroll
        for (int n = 0; n < 8; ++n) {
            float4 c = *(const float4*)&rs[n][i4];
            y2[n] = fmaf(c.x, w0, y2[n]); y2[n] = fmaf(c.y, w1, y2[n]);
            y2[n] = fmaf(c.z, w2, y2[n]); y2[n] = fmaf(c.w, w3, y2[n]);
        }
    }
    #pragma unroll
    for (int n = 0; n < 8; ++n)
        qout[(long)(n0 + n) * 128 + tid] = y2[n];
}

// ---------------- fused MFMA edge kernel (B direct from global, 3 blocks/CU) ----------------
// 64 edges/block, 4 waves. GEMM1: [64,352]x[352,256]; LN+ReLU; GEMM2: [64,128]x[128,256]
// LDS map (bytes), total 51712 -> rounds to 53248 -> 3 blocks/CU:
//   0      .. 46080 : A1 bf16 [64][360]   (alias: A2 [64][264] in [0..33792), vbuf [64][136] in [0..17408))
//   33792  .. 34816 : ln_s f32 [4][64]    (transient: between barriers 2-4; A1 dead, A2/qbuf not yet)
//   34816  .. 35840 : ln_q f32 [4][64]    (transient)
//   17408  .. 51200 : qbuf f32 [64][132]  (epilogue only)
//   51200  .. 51456 : ew_s f32 [64]
//   51456  .. 51712 : dst_s int [64]
__global__ __launch_bounds__(256, 3) void edge_kernel(
    const float* __restrict__ h, const float* __restrict__ r_feat,
    const float* __restrict__ edge_feat, const int* __restrict__ edge_index,
    const short* __restrict__ Wt1, const short* __restrict__ Wt2,
    const float* __restrict__ kb1, const float* __restrict__ kg1,
    const float* __restrict__ kbe1, const float* __restrict__ kb2,
    const float* __restrict__ vb1, const float* __restrict__ vg1,
    const float* __restrict__ vbe1, const float* __restrict__ vb2,
    const float* __restrict__ ewW, const float* __restrict__ ewb,
    const float* __restrict__ q,
    float* __restrict__ logits_g, short* __restrict__ voutS)
{
    __shared__ __align__(16) char smem[51712];
    short* A1   = (short*)smem;                 // [64][360]
    short* A2   = (short*)smem;                 // [64][264]
    short* vbuf = (short*)smem;                 // [64][136]
    float* qbuf = (float*)(smem + 17408);       // [64][132]
    float* ln_s = (float*)(smem + 33792);       // [4][64] transient
    float* ln_q = (float*)(smem + 34816);       // [4][64] transient
    float* ew_s = (float*)(smem + 51200);       // [64]
    int*   dst_s= (int*)(smem + 51456);         // [64]

    const int tid  = threadIdx.x;
    const int w    = tid >> 6;          // wave 0..3
    const int lane = tid & 63;
    const int g    = lane >> 4;         // 0..3
    const int lr   = lane & 15;
    const int cw   = w * 64;            // this wave's output-col base (0..255)
    const long eg0 = (long)blockIdx.x * 64;

    // ---- stage A1 (gather + f32->bf16) : 4 lanes per row ----
    {
        int row = tid >> 2;             // 0..63
        int c4  = tid & 3;
        long eg = eg0 + row;
        int srcn = edge_index[eg];
        int dstn = edge_index[N_EDGES + eg];
        if (c4 == 0) dst_s[row] = dstn;
        short* arow = A1 + row * 360;
        if (c4 == 0) {
            float4 v = *(const float4*)&edge_feat[eg * 4];
            st_bf4(arow, v);
        }
        #pragma unroll
        for (int j = 0; j < 4; ++j) {
            float4 v = *(const float4*)&r_feat[eg * 64 + c4 * 16 + j * 4];
            st_bf4(arow + 4 + c4 * 16 + j * 4, v);
        }
        #pragma unroll
        for (int j = 0; j < 8; ++j) {
            float4 v = *(const float4*)&h[(size_t)dstn * 128 + c4 * 32 + j * 4];
            st_bf4(arow + 68 + c4 * 32 + j * 4, v);
        }
        #pragma unroll
        for (int j = 0; j < 8; ++j) {
            float4 v = *(const float4*)&h[(size_t)srcn * 128 + c4 * 32 + j * 4];
            st_bf4(arow + 196 + c4 * 32 + j * 4, v);
        }
        for (int gi = c4; gi < 9; gi += 4)
            *(int2*)(arow + 324 + gi * 4) = make_int2(0, 0);

        // e_w = sigmoid(r_feat . ewW + b)
        float p = 0.f;
        #pragma unroll
        for (int j = 0; j < 4; ++j) {
            float4 rv = *(const float4*)&r_feat[eg * 64 + c4 * 16 + j * 4];
            float4 wv = *(const float4*)&ewW[c4 * 16 + j * 4];
            p += rv.x * wv.x + rv.y * wv.y + rv.z * wv.z + rv.w * wv.w;
        }
        p += __shfl_xor(p, 1);
        p += __shfl_xor(p, 2);
        if (c4 == 0) ew_s[row] = 1.f / (1.f + expf(-(p + ewb[0])));
    }
    __syncthreads();   // barrier 1: A1 / ew_s / dst_s ready

    f32x4 acc[4][4];
    const f32x4 zero4 = {0.f, 0.f, 0.f, 0.f};
    #pragma unroll
    for (int mf = 0; mf < 4; ++mf)
        #pragma unroll
        for (int nf = 0; nf < 4; ++nf) acc[mf][nf] = zero4;

    // ---- GEMM1: K = 11 chunks of 32, B fragments straight from global (L2) ----
    #pragma unroll 2
    for (int ks = 0; ks < 11; ++ks) {
        bf16x8 bfr[4], afr[4];
        const short* wb = Wt1 + (size_t)ks * 8192 + (cw + lr) * 32 + g * 8;
        #pragma unroll
        for (int nf = 0; nf < 4; ++nf)
            bfr[nf] = *(const bf16x8*)(wb + nf * 512);
        #pragma unroll
        for (int mf = 0; mf < 4; ++mf)
            afr[mf] = *(const bf16x8*)&A1[(mf * 16 + lr) * 360 + ks * 32 + g * 8];
        #pragma unroll
        for (int mf = 0; mf < 4; ++mf)
            #pragma unroll
            for (int nf = 0; nf < 4; ++nf)
                acc[mf][nf] = __builtin_amdgcn_mfma_f32_16x16x32_bf16(
                    afr[mf], bfr[nf], acc[mf][nf], 0, 0, 0);
    }

    // ---- bias + row sums (registers only) ----
    const float* b1p  = (w < 2) ? kb1  : vb1;
    const float* g1p  = (w < 2) ? kg1  : vg1;
    const float* be1p = (w < 2) ? kbe1 : vbe1;
    const float* b2p  = (w < 2) ? kb2  : vb2;
    const int colm0 = cw & 127;
    float b1c[4], g1c[4], be1c[4], b2c[4];
    #pragma unroll
    for (int nf = 0; nf < 4; ++nf) {
        int cm = colm0 + nf * 16 + lr;
        b1c[nf] = b1p[cm]; g1c[nf] = g1p[cm]; be1c[nf] = be1p[cm]; b2c[nf] = b2p[cm];
    }
    float sum_[4][4], sq_[4][4];
    #pragma unroll
    for (int mf = 0; mf < 4; ++mf)
        #pragma unroll
        for (int r = 0; r < 4; ++r) { sum_[mf][r] = 0.f; sq_[mf][r] = 0.f; }
    #pragma unroll
    for (int mf = 0; mf < 4; ++mf)
        #pragma unroll
        for (int nf = 0; nf < 4; ++nf)
            #pragma unroll
            for (int r = 0; r < 4; ++r) {
                float a = acc[mf][nf][r] + b1c[nf];
                acc[mf][nf][r] = a;
                sum_[mf][r] += a;
                sq_[mf][r]  += a * a;
            }
    #pragma unroll
    for (int mf = 0; mf < 4; ++mf)
        #pragma unroll
        for (int r = 0; r < 4; ++r) {
            float s = sum_[mf][r], qq = sq_[mf][r];
            #pragma unroll
            for (int m = 1; m < 16; m <<= 1) {
                s  += __shfl_xor(s, m);
                qq += __shfl_xor(qq, m);
            }
            sum_[mf][r] = s; sq_[mf][r] = qq;
        }
    __syncthreads();   // barrier 2: all GEMM1 A1-reads done -> ln region (A1 tail) safe to write
    if (lr == 0) {
        #pragma unroll
        for (int mf = 0; mf < 4; ++mf)
            #pragma unroll
            for (int r = 0; r < 4; ++r) {
                int row = mf * 16 + g * 4 + r;
                ln_s[w * 64 + row] = sum_[mf][r];
                ln_q[w * 64 + row] = sq_[mf][r];
            }
    }
    __syncthreads();   // barrier 3: ln partials ready
    #pragma unroll
    for (int mf = 0; mf < 4; ++mf)
        #pragma unroll
        for (int r = 0; r < 4; ++r) {
            int row = mf * 16 + g * 4 + r;
            float mu  = (ln_s[w * 64 + row] + ln_s[(w ^ 1) * 64 + row]) * 0.0078125f;
            float ex2 = (ln_q[w * 64 + row] + ln_q[(w ^ 1) * 64 + row]) * 0.0078125f;
            float rs = rsqrtf(ex2 - mu * mu + 1e-5f);
            #pragma unroll
            for (int nf = 0; nf < 4; ++nf) {
                float nv = fmaxf((acc[mf][nf][r] - mu) * rs * g1c[nf] + be1c[nf], 0.f);
                A2[row * 264 + cw + nf * 16 + lr] = f2bf(nv);
            }
        }
    __syncthreads();   // barrier 4: A2 ready

    // ---- GEMM2: K = 4 chunks of 32 (waves 0,1: k-out; waves 2,3: v-out) ----
    #pragma unroll
    for (int mf = 0; mf < 4; ++mf)
        #pragma unroll
        for (int nf = 0; nf < 4; ++nf) acc[mf][nf] = zero4;
    const int kbase = (w < 2) ? 0 : 128;
    #pragma unroll 2
    for (int ks = 0; ks < 4; ++ks) {
        bf16x8 bfr[4], afr[4];
        const short* wb = Wt2 + (size_t)ks * 8192 + (cw + lr) * 32 + g * 8;
        #pragma unroll
        for (int nf = 0; nf < 4; ++nf)
            bfr[nf] = *(const bf16x8*)(wb + nf * 512);
        #pragma unroll
        for (int mf = 0; mf < 4; ++mf)
            afr[mf] = *(const bf16x8*)&A2[(mf * 16 + lr) * 264 + kbase + ks * 32 + g * 8];
        #pragma unroll
        for (int mf = 0; mf < 4; ++mf)
            #pragma unroll
            for (int nf = 0; nf < 4; ++nf)
                acc[mf][nf] = __builtin_amdgcn_mfma_f32_16x16x32_bf16(
                    afr[mf], bfr[nf], acc[mf][nf], 0, 0, 0);
    }
    __syncthreads();   // barrier 5: GEMM2 done, A-region free for vbuf/qbuf overlay

    // ---- stage q rows (f32) for logits ----
    {
        int row = tid >> 2, c4 = tid & 3;
        int dstn = dst_s[row];
        #pragma unroll
        for (int j = 0; j < 8; ++j)
            *(float4*)&qbuf[row * 132 + c4 * 32 + j * 4] =
                *(const float4*)&q[(size_t)dstn * 128 + c4 * 32 + j * 4];
    }
    // ---- waves 2,3: v2 = (acc + b2) * e_w -> vbuf bf16 ----
    if (w >= 2) {
        #pragma unroll
        for (int mf = 0; mf < 4; ++mf)
            #pragma unroll
            for (int r = 0; r < 4; ++r) {
                int row = mf * 16 + g * 4 + r;
                float ew = ew_s[row];
                #pragma unroll
                for (int nf = 0; nf < 4; ++nf) {
                    float vv = (acc[mf][nf][r] + b2c[nf]) * ew;
                    vbuf[row * 136 + (cw - 128) + nf * 16 + lr] = f2bf(vv);
                }
            }
    }
    __syncthreads();   // barrier 6: vbuf + qbuf ready

    // ---- waves 0,1: logits ----
    if (w < 2) {
        #pragma unroll
        for (int mf = 0; mf < 4; ++mf)
            #pragma unroll
            for (int nf = 0; nf < 4; ++nf)
                #pragma unroll
                for (int r = 0; r < 4; ++r) {
                    int row = mf * 16 + g * 4 + r;
                    int col = cw + nf * 16 + lr;
                    float k2 = acc[mf][nf][r] + b2c[nf];
                    float p = k2 * qbuf[row * 132 + col];
                    p += __shfl_xor(p, 1);
                    p += __shfl_xor(p, 2);
                    p += __shfl_xor(p, 4);
                    if ((lane & 7) == 0) {
                        int head = col >> 3;
                        long eg = eg0 + row;
                        logits_g[eg * 16 + head] = p * 0.35355339059327373f;
                    }
                }
    }
    // ---- coalesced vout store: 64 rows x 128 bf16 = 1024 int4 ----
    #pragma unroll
    for (int i = tid; i < 1024; i += 256) {
        int row = i >> 4, p8 = i & 15;
        *(int4*)&voutS[(eg0 + row) * 128 + p8 * 8] = *(const int4*)&vbuf[row * 136 + p8 * 8];
    }
}

// ---------------- gather: per-dst softmax + weighted V sum (ids staged in LDS) ----------------
__global__ __launch_bounds__(128) void gather_kernel(
    const int* __restrict__ base, const int* __restrict__ cnt,
    const int* __restrict__ sorted,
    const float* __restrict__ logits, const __hip_bfloat16* __restrict__ vout,
    float* __restrict__ msg)
{
    __shared__ int eids[512];
    int d = blockIdx.x, t = threadIdx.x;
    int hd = t >> 3;
    int s = base[d], c = cnt[d];

    for (int i = t; i < c && i < 512; i += 128) eids[i] = sorted[s + i];
    __syncthreads();

    // phase 1: per-head max (8 lanes stride the edge list, then xor-reduce)
    float m = -3.402823466e+38f;
    for (int i = (t & 7); i < c; i += 8) {
        int e = (i < 512) ? eids[i] : sorted[s + i];
        m = fmaxf(m, logits[(long)e * 16 + hd]);
    }
    m = fmaxf(m, __shfl_xor(m, 1));
    m = fmaxf(m, __shfl_xor(m, 2));
    m = fmaxf(m, __shfl_xor(m, 4));

    // phase 2: accumulate exp-weighted v (each thread owns one output dim)
    float acc = 0.f, den = 0.f;
    #pragma unroll 2
    for (int i = 0; i < c; ++i) {
        int e = (i < 512) ? eids[i] : sorted[s + i];
        float ex = expf(logits[(long)e * 16 + hd] - m);
        den += ex;
        acc += ex * __bfloat162float(vout[(long)e * 128 + t]);
    }
    msg[(long)d * 128 + t] = acc / (den + 1e-16f);
}

// ---------------- output MLP + residual, 8 nodes/block ----------------
__global__ __launch_bounds__(128) void out_kernel(
    const float* __restrict__ h, const float* __restrict__ msg,
    const float* __restrict__ W1, const float* __restrict__ b1,
    const float* __restrict__ g1, const float* __restrict__ be1,
    const float* __restrict__ W2, const float* __restrict__ b2,
    float* __restrict__ out)
{
    __shared__ __align__(16) float xin[8][256];
    __shared__ __align__(16) float rbuf[8][128];
    __shared__ float4 red4[2];
    int n0 = blockIdx.x * 8, tid = threadIdx.x;
    float hv[8];
    #pragma unroll
    for (int n = 0; n < 8; ++n) {
        hv[n] = h[(long)(n0 + n) * 128 + tid];
        xin[n][tid] = msg[(long)(n0 + n) * 128 + tid];
        xin[n][128 + tid] = hv[n];
    }
    __syncthreads();
    float y[8];
    {
        float b = b1[tid];
        #pragma unroll
        for (int n = 0; n < 8; ++n) y[n] = b;
    }
    for (int i4 = 0; i4 < 256; i4 += 4) {
        float w0 = W1[(i4 + 0) * 128 + tid], w1 = W1[(i4 + 1) * 128 + tid];
        float w2 = W1[(i4 + 2) * 128 + tid], w3 = W1[(i4 + 3) * 128 + tid];
        #pragma unroll
        for (int n = 0; n < 8; ++n) {
            float4 c = *(const float4*)&xin[n][i4];
            y[n] = fmaf(c.x, w0, y[n]); y[n] = fmaf(c.y, w1, y[n]);
            y[n] = fmaf(c.z, w2, y[n]); y[n] = fmaf(c.w, w3, y[n]);
        }
    }
    float gv = g1[tid], bev = be1[tid];
    #pragma unroll 1
    for (int p = 0; p < 4; ++p) {
        int na = 2 * p, nb = 2 * p + 1;
        float4 s = make_float4(y[na], y[na] * y[na], y[nb], y[nb] * y[nb]);
        block_reduce4(s, red4);
        float muA = s.x * 0.0078125f, vA = s.y * 0.0078125f - muA * muA;
        float muB = s.z * 0.0078125f, vB = s.w * 0.0078125f - muB * muB;
        rbuf[na][tid] = fmaxf((y[na] - muA) * rsqrtf(vA + 1e-5f) * gv + bev, 0.f);
        rbuf[nb][tid] = fmaxf((y[nb] - muB) * rsqrtf(vB + 1e-5f) * gv + bev, 0.f);
    }
    __syncthreads();
    float y2[8];
    {
        float b = b2[tid];
        #pragma unroll
        for (int n = 0; n < 8; ++n) y2[n] = b;
    }
    for (int i4 = 0; i4 < 128; i4 += 4) {
        float w0 = W2[(i4 + 0) * 128 + tid], w1 = W2[(i4 + 1) * 128 + tid];
        float w2 = W2[(i4 + 2) * 128 + tid], w3 = W2[(i4 + 3) * 128 + tid];
        #pragma unroll
        for (int n = 0; n < 8; ++n) {
            float4 c = *(const float4*)&rbuf[n][i4];
            y2[n] = fmaf(c.x, w0, y2[n]); y2[n] = fmaf(c.y, w1, y2[n]);
            y2[n] = fmaf(c.z, w2, y2[n]); y2[n] = fmaf(c.w, w3, y2[n]);
        }
    }
    #pragma unroll
    for (int n = 0; n < 8; ++n)
        out[(long)(n0 + n) * 128 + tid] = y2[n] + hv[n];
}

// ---------------- host ----------------
extern "C" void kernel_launch(void* const* d_in, const int* in_sizes, int n_in,
                              void* d_out, int out_size, void* d_ws, size_t ws_size,
                              hipStream_t stream) {
    (void)in_sizes; (void)n_in; (void)out_size; (void)ws_size;
    const float* h         = (const float*)d_in[0];
    const float* r_feat    = (const float*)d_in[1];
    const float* edge_feat = (const float*)d_in[2];
    const int*   edge_index= (const int*)d_in[3];
    const float* kW1 = (const float*)d_in[4],  *kb1 = (const float*)d_in[5];
    const float* kg1 = (const float*)d_in[6],  *kbe1= (const float*)d_in[7];
    const float* kW2 = (const float*)d_in[8],  *kb2 = (const float*)d_in[9];
    const float* vW1 = (const float*)d_in[10], *vb1 = (const float*)d_in[11];
    const float* vg1 = (const float*)d_in[12], *vbe1= (const float*)d_in[13];
    const float* vW2 = (const float*)d_in[14], *vb2 = (const float*)d_in[15];
    const float* qW1 = (const float*)d_in[16], *qb1 = (const float*)d_in[17];
    const float* qg1 = (const float*)d_in[18], *qbe1= (const float*)d_in[19];
    const float* qW2 = (const float*)d_in[20], *qb2 = (const float*)d_in[21];
    const float* oW1 = (const float*)d_in[22], *ob1 = (const float*)d_in[23];
    const float* og1 = (const float*)d_in[24], *obe1= (const float*)d_in[25];
    const float* oW2 = (const float*)d_in[26], *ob2 = (const float*)d_in[27];
    const float* ewW = (const float*)d_in[28], *ewb = (const float*)d_in[29];
    float* out = (float*)d_out;

    char* ws = (char*)d_ws;
    float* q      = (float*)(ws);                     // [N,128] f32 ; aliased by msg after edge_kernel
    float* msg    = (float*)(ws);                     //   (gather writes after last q read)
    float* logits = (float*)(ws + 5120000);           // [E,16] f32
    short* voutS  = (short*)(ws + 25600000);          // [E,128] bf16
    short* Wt1    = (short*)(ws + 107520000);         // 11*256*32*2 = 180,224 B
    short* Wt2    = (short*)(ws + 107700224);         // 4*256*32*2  =  65,536 B
    int*   cnt    = (int*)(ws + 107765760);           // [N]
    int*   base   = (int*)(ws + 107805760);           // [N]
    int*   cursor = (int*)(ws + 107845760);           // [N]
    int*   sorted = (int*)(ws + 107885760);           // [E]

    hipMemsetAsync(cnt, 0, N_NODES * 4, stream);

    // CSR build (depends only on edge_index)
    hist_kernel<<<1250, 256, 0, stream>>>(edge_index, cnt);
    scan_kernel<<<1, 256, 0, stream>>>(cnt, base, cursor);
    scatter_ids_kernel<<<1250, 256, 0, stream>>>(edge_index, cursor, sorted);

    prep_wt_kernel<<<11, 256, 0, stream>>>(kW1, vW1, Wt1, 324);
    prep_wt_kernel<<<4, 256, 0, stream>>>(kW2, vW2, Wt2, 128);

    q_kernel<<<N_NODES / 8, 128, 0, stream>>>(h, qW1, qb1, qg1, qbe1, qW2, qb2, q);

    edge_kernel<<<N_EDGES / 64, 256, 0, stream>>>(
        h, r_feat, edge_feat, edge_index, Wt1, Wt2,
        kb1, kg1, kbe1, kb2, vb1, vg1, vbe1, vb2,
        ewW, ewb, q, logits, voutS);

    gather_kernel<<<N_NODES, 128, 0, stream>>>(base, cnt, sorted, logits,
        (const __hip_bfloat16*)voutS, msg);

    out_kernel<<<N_NODES / 8, 128, 0, stream>>>(h, msg, oW1, ob1, og1, obe1, oW2, ob2, out);
}